// Round 1
// baseline (291.746 us; speedup 1.0000x reference)
//
#include <hip/hip_runtime.h>
#include <hip/hip_bf16.h>
#include <cstdint>
#include <cstddef>

// Problem constants
#define B_  8192
#define D_  256
#define H_  512
#define K_  1280   // D + 2H
#define N_  2560   // 5H

typedef short short8 __attribute__((ext_vector_type(8)));
typedef float f32x4  __attribute__((ext_vector_type(4)));

__device__ __forceinline__ float sigf(float x)     { return 1.f / (1.f + __expf(-x)); }
__device__ __forceinline__ float tanhfast(float x) { return 1.f - 2.f / (__expf(2.f * x) + 1.f); }

// ---------------------------------------------------------------------------
// convA: pack [x | h_t | h_s] -> bf16 A[B_, K_]
// ---------------------------------------------------------------------------
__global__ void convA_kernel(const float* __restrict__ x, const float* __restrict__ ht,
                             const float* __restrict__ hs, __hip_bfloat16* __restrict__ A) {
    int idx = blockIdx.x * 256 + threadIdx.x;  // over B_*K_ (exact multiple)
    int b = idx / K_;
    int k = idx - b * K_;
    float v;
    if (k < D_)            v = x[b * D_ + k];
    else if (k < D_ + H_)  v = ht[b * H_ + (k - D_)];
    else                   v = hs[b * H_ + (k - D_ - H_)];
    A[idx] = __float2bfloat16(v);
}

// ---------------------------------------------------------------------------
// convW: build bf16 W^T[N_, K_] (row n = gate*512+h, cols = k) via LDS transpose
// source: per-gate U[256,512], Wt[512,512], Ws[512,512] row-major (k-major, h contiguous)
// ---------------------------------------------------------------------------
struct WPtrs {
    const float* U[5];
    const float* Wt[5];
    const float* Ws[5];
};

__global__ void convW_kernel(WPtrs p, __hip_bfloat16* __restrict__ WT) {
    __shared__ __hip_bfloat16 tile[64][72];  // padded to dodge bank conflicts
    int g  = blockIdx.z;
    int k0 = blockIdx.y * 64;
    int h0 = blockIdx.x * 64;
    const float* src; int kl0;
    if (k0 < 256)      { src = p.U[g];  kl0 = k0; }
    else if (k0 < 768) { src = p.Wt[g]; kl0 = k0 - 256; }
    else               { src = p.Ws[g]; kl0 = k0 - 768; }
    int tid = threadIdx.x;
    int tk = tid >> 6;    // 0..3
    int th = tid & 63;
    for (int r = 0; r < 16; ++r) {
        int kl = r * 4 + tk;
        tile[kl][th] = __float2bfloat16(src[(size_t)(kl0 + kl) * H_ + h0 + th]);
    }
    __syncthreads();
    for (int r = 0; r < 16; ++r) {
        int nl = r * 4 + tk;  // h index within tile
        int kk = th;          // k index within tile
        WT[(size_t)(g * H_ + h0 + nl) * K_ + k0 + kk] = tile[kk][nl];
    }
}

// ---------------------------------------------------------------------------
// GEMM: gates[B_, N_] = A[B_, K_] @ W  (W^T stored [N_, K_])
// m97 structure: 128x128 tile, BK=32, 256 threads = 4 waves (2x2), each wave
// 64x64 = 4x4 frags of mfma_f32_16x16x32_bf16, global_load_lds width 16.
// ---------------------------------------------------------------------------
#define GLD16(gp, lp)                                                              \
    __builtin_amdgcn_global_load_lds(                                              \
        (const __attribute__((address_space(1))) unsigned int*)(gp),               \
        (__attribute__((address_space(3))) unsigned int*)(lp), 16, 0, 0)

__global__ __launch_bounds__(256) void gemm_kernel(const __hip_bfloat16* __restrict__ A,
                                                   const __hip_bfloat16* __restrict__ WT,
                                                   float* __restrict__ gates) {
    __shared__ alignas(16) unsigned short As[128 * 32];
    __shared__ alignas(16) unsigned short Bs[128 * 32];

    int tid = threadIdx.x;
    int m0 = blockIdx.y * 128;
    int n0 = blockIdx.x * 128;
    int wid  = tid >> 6, lane = tid & 63;
    int wm   = wid >> 1, wn   = wid & 1;
    int quad = lane >> 4, l15 = lane & 15;

    f32x4 acc[4][4];
    for (int i = 0; i < 4; ++i)
        for (int j = 0; j < 4; ++j)
            acc[i][j] = (f32x4){0.f, 0.f, 0.f, 0.f};

    // staging: thread t loads 16B from row (t>>2) col (t&3)*8, issues 0/1 offset by 64 rows
    int srow = tid >> 2;
    int scol = (tid & 3) * 8;
    const __hip_bfloat16* Abase = A  + (size_t)(m0 + srow) * K_ + scol;
    const __hip_bfloat16* Bbase = WT + (size_t)(n0 + srow) * K_ + scol;
    unsigned short* AsDst = As + tid * 8;   // byte offset tid*16 (wave base + lane*16)
    unsigned short* BsDst = Bs + tid * 8;

    for (int k0 = 0; k0 < K_; k0 += 32) {
        GLD16(Abase + k0,                   AsDst);
        GLD16(Abase + k0 + (size_t)64 * K_, AsDst + 2048);
        GLD16(Bbase + k0,                   BsDst);
        GLD16(Bbase + k0 + (size_t)64 * K_, BsDst + 2048);
        __syncthreads();

        short8 a[4], b[4];
        for (int f = 0; f < 4; ++f) {
            a[f] = *(const short8*)(As + (wm * 64 + f * 16 + l15) * 32 + quad * 8);
            b[f] = *(const short8*)(Bs + (wn * 64 + f * 16 + l15) * 32 + quad * 8);
        }
        for (int i = 0; i < 4; ++i)
            for (int j = 0; j < 4; ++j)
                acc[i][j] = __builtin_amdgcn_mfma_f32_16x16x32_bf16(a[i], b[j], acc[i][j], 0, 0, 0);
        __syncthreads();
    }

    // epilogue store: C/D layout col=lane&15, row=quad*4+reg
    for (int i = 0; i < 4; ++i) {
        int row0 = m0 + wm * 64 + i * 16 + quad * 4;
        for (int j = 0; j < 4; ++j) {
            int col = n0 + wn * 64 + j * 16 + l15;
            for (int r = 0; r < 4; ++r)
                gates[(size_t)(row0 + r) * N_ + col] = acc[i][j][r];
        }
    }
}

// ---------------------------------------------------------------------------
// Elementwise LSTM epilogue
// ---------------------------------------------------------------------------
__global__ void epilogue_kernel(const float* __restrict__ gates,
                                const float* __restrict__ ct, const float* __restrict__ cs,
                                const float* __restrict__ bi, const float* __restrict__ bs,
                                const float* __restrict__ bt, const float* __restrict__ bo,
                                const float* __restrict__ bc,
                                float* __restrict__ out) {
    int idx = blockIdx.x * 256 + threadIdx.x;  // over B_*H_ (exact multiple)
    int b = idx >> 9;
    int h = idx & (H_ - 1);
    const float* grow = gates + (size_t)b * N_;
    float gi  = grow[h]           + bi[h];
    float gfs = grow[H_ + h]      + bs[h];
    float gft = grow[2 * H_ + h]  + bt[h];
    float go  = grow[3 * H_ + h]  + bo[h];
    float gc  = grow[4 * H_ + h]  + bc[h];
    float i_n = sigf(gi), fs_n = sigf(gfs), ft_n = sigf(gft), o_n = sigf(go);
    float c_n = tanhfast(gc);
    float ch  = i_n * c_n + ft_n * ct[idx] + fs_n * cs[idx];
    out[idx] = o_n * tanhfast(ch);
    out[(size_t)B_ * H_ + idx] = ch;
}

// ---------------------------------------------------------------------------
// Fallback (ws too small): one block per row, fp32 direct. Slow but correct.
// ---------------------------------------------------------------------------
struct AllW {
    const float* U[5];
    const float* Wt[5];
    const float* Ws[5];
    const float* bias[5];
};

__global__ __launch_bounds__(512) void fallback_kernel(const float* __restrict__ x,
                                                       const float* __restrict__ ht,
                                                       const float* __restrict__ hs,
                                                       const float* __restrict__ ct,
                                                       const float* __restrict__ cs,
                                                       AllW w, float* __restrict__ out) {
    __shared__ float arow[K_];
    int b = blockIdx.x;
    int h = threadIdx.x;
    for (int k = h; k < K_; k += 512) {
        float v;
        if (k < D_)           v = x[b * D_ + k];
        else if (k < D_ + H_) v = ht[b * H_ + k - D_];
        else                  v = hs[b * H_ + k - D_ - H_];
        arow[k] = v;
    }
    __syncthreads();
    float g[5];
    for (int gi = 0; gi < 5; ++gi) {
        float s = w.bias[gi][h];
        const float* U = w.U[gi];
        for (int k = 0; k < D_; ++k) s += arow[k] * U[(size_t)k * H_ + h];
        const float* Wt = w.Wt[gi];
        for (int k = 0; k < H_; ++k) s += arow[D_ + k] * Wt[(size_t)k * H_ + h];
        const float* Ws = w.Ws[gi];
        for (int k = 0; k < H_; ++k) s += arow[D_ + H_ + k] * Ws[(size_t)k * H_ + h];
        g[gi] = s;
    }
    int idx = b * H_ + h;
    float i_n = sigf(g[0]), fs_n = sigf(g[1]), ft_n = sigf(g[2]), o_n = sigf(g[3]);
    float c_n = tanhfast(g[4]);
    float ch  = i_n * c_n + ft_n * ct[idx] + fs_n * cs[idx];
    out[idx] = o_n * tanhfast(ch);
    out[(size_t)B_ * H_ + idx] = ch;
}

// ---------------------------------------------------------------------------
extern "C" void kernel_launch(void* const* d_in, const int* in_sizes, int n_in,
                              void* d_out, int out_size, void* d_ws, size_t ws_size,
                              hipStream_t stream) {
    const float* x  = (const float*)d_in[0];
    const float* ht = (const float*)d_in[1];
    const float* hs = (const float*)d_in[2];
    const float* ct = (const float*)d_in[3];
    const float* cs = (const float*)d_in[4];

    // weights: d_in[5 + g*4 + {0:U, 1:Wt, 2:Ws, 3:b}], gates g = i, s(f_s), t(f_t), o, c
    WPtrs wp;
    AllW  aw;
    for (int g = 0; g < 5; ++g) {
        wp.U[g]    = (const float*)d_in[5 + g * 4 + 0];
        wp.Wt[g]   = (const float*)d_in[5 + g * 4 + 1];
        wp.Ws[g]   = (const float*)d_in[5 + g * 4 + 2];
        aw.U[g]    = wp.U[g];
        aw.Wt[g]   = wp.Wt[g];
        aw.Ws[g]   = wp.Ws[g];
        aw.bias[g] = (const float*)d_in[5 + g * 4 + 3];
    }
    float* out = (float*)d_out;

    size_t szA = (size_t)B_ * K_ * 2;  // 20 MB
    size_t szW = (size_t)N_ * K_ * 2;  // 6.25 MB
    size_t szG = (size_t)B_ * N_ * 4;  // 80 MB

    if (ws_size >= szA + szW + szG) {
        __hip_bfloat16* Abf = (__hip_bfloat16*)d_ws;
        __hip_bfloat16* WT  = (__hip_bfloat16*)((char*)d_ws + szA);
        float*          gts = (float*)((char*)d_ws + szA + szW);

        convA_kernel<<<(B_ * K_) / 256, 256, 0, stream>>>(x, ht, hs, Abf);
        convW_kernel<<<dim3(8, 20, 5), 256, 0, stream>>>(wp, WT);
        gemm_kernel<<<dim3(N_ / 128, B_ / 128), 256, 0, stream>>>(Abf, WT, gts);
        epilogue_kernel<<<(B_ * H_) / 256, 256, 0, stream>>>(
            gts, ct, cs, aw.bias[0], aw.bias[1], aw.bias[2], aw.bias[3], aw.bias[4], out);
    } else {
        fallback_kernel<<<B_, 512, 0, stream>>>(x, ht, hs, ct, cs, aw, out);
    }
}

// Round 3
// 248.155 us; speedup vs baseline: 1.1757x; 1.1757x over previous
//
#include <hip/hip_runtime.h>
#include <hip/hip_bf16.h>
#include <cstdint>
#include <cstddef>

// Problem constants
#define B_  8192
#define D_  256
#define H_  512
#define K_  1280   // D + 2H
#define N_  2560   // 5H
#define NT_ 160    // N-tile: 2 h-groups of (16 h x 5 gates)

typedef short short8 __attribute__((ext_vector_type(8)));
typedef float f32x4  __attribute__((ext_vector_type(4)));

__device__ __forceinline__ float sigf(float x)     { return 1.f / (1.f + __expf(-x)); }
__device__ __forceinline__ float tanhfast(float x) { return 1.f - 2.f / (__expf(2.f * x) + 1.f); }

// ---------------------------------------------------------------------------
// convA: pack [x | h_t | h_s] -> bf16 A[B_, K_], 8 elems/thread.
// Segment starts (0,256,768) are 8-aligned so an 8-chunk never straddles.
// ---------------------------------------------------------------------------
__global__ void convA_kernel(const float* __restrict__ x, const float* __restrict__ ht,
                             const float* __restrict__ hs, __hip_bfloat16* __restrict__ A) {
    int t = blockIdx.x * 256 + threadIdx.x;   // over B_*K_/8 (exact multiple)
    int idx8 = t * 8;
    int b = idx8 / K_;
    int k = idx8 - b * K_;
    const float* src;
    if (k < D_)            src = x  + (size_t)b * D_ + k;
    else if (k < D_ + H_)  src = ht + (size_t)b * H_ + (k - D_);
    else                   src = hs + (size_t)b * H_ + (k - D_ - H_);
    f32x4 v0 = *(const f32x4*)(src);
    f32x4 v1 = *(const f32x4*)(src + 4);
    union { short8 s; __hip_bfloat16 h[8]; } o;
    o.h[0] = __float2bfloat16(v0[0]); o.h[1] = __float2bfloat16(v0[1]);
    o.h[2] = __float2bfloat16(v0[2]); o.h[3] = __float2bfloat16(v0[3]);
    o.h[4] = __float2bfloat16(v1[0]); o.h[5] = __float2bfloat16(v1[1]);
    o.h[6] = __float2bfloat16(v1[2]); o.h[7] = __float2bfloat16(v1[3]);
    *(short8*)(A + idx8) = o.s;
}

// ---------------------------------------------------------------------------
// convW: build bf16 WT[n', k], n' = (h/16)*80 + g*16 + (h%16)  (gate-interleaved)
// via 64x64 LDS tile transpose per (gate, k-block, h-block).
// ---------------------------------------------------------------------------
struct WPtrs {
    const float* U[5];
    const float* Wt[5];
    const float* Ws[5];
};

__global__ void convW_kernel(WPtrs p, __hip_bfloat16* __restrict__ WT) {
    __shared__ __hip_bfloat16 tile[64][72];  // padded
    int g  = blockIdx.z;
    int k0 = blockIdx.y * 64;
    int h0 = blockIdx.x * 64;
    const float* src; int kl0;
    if (k0 < 256)      { src = p.U[g];  kl0 = k0; }
    else if (k0 < 768) { src = p.Wt[g]; kl0 = k0 - 256; }
    else               { src = p.Ws[g]; kl0 = k0 - 768; }
    int tid = threadIdx.x;
    int tk = tid >> 6;    // 0..3
    int th = tid & 63;
    for (int r = 0; r < 16; ++r) {
        int kl = r * 4 + tk;
        tile[kl][th] = __float2bfloat16(src[(size_t)(kl0 + kl) * H_ + h0 + th]);
    }
    __syncthreads();
    for (int r = 0; r < 16; ++r) {
        int hl = r * 4 + tk;           // h within tile
        int h  = h0 + hl;
        int np = (h >> 4) * 80 + g * 16 + (h & 15);
        WT[(size_t)np * K_ + k0 + th] = tile[th][hl];
    }
}

// ---------------------------------------------------------------------------
// Fused GEMM + LSTM epilogue.
// gates[B_, N'_perm] = A @ W_perm; block tile M=128 x N'=160 (= 32 h x 5 gates),
// 4 waves 2x2: wave = M64 x N80 (one h-group: 16 h x 5 gates).
// After K-loop each lane holds all 5 gates of its (row,h) -> lane-local LSTM.
// ---------------------------------------------------------------------------
#define GLD16(gp, lp)                                                              \
    __builtin_amdgcn_global_load_lds(                                              \
        (const __attribute__((address_space(1))) unsigned int*)(gp),               \
        (__attribute__((address_space(3))) unsigned int*)(lp), 16, 0, 0)

__global__ __launch_bounds__(256) void gemm_fused_kernel(
    const __hip_bfloat16* __restrict__ A, const __hip_bfloat16* __restrict__ WT,
    const float* __restrict__ ct, const float* __restrict__ cs,
    const float* __restrict__ bi, const float* __restrict__ bfs,
    const float* __restrict__ bft, const float* __restrict__ bo,
    const float* __restrict__ bc, float* __restrict__ out) {
    __shared__ alignas(16) unsigned short sA[128 * 32];
    __shared__ alignas(16) unsigned short sB[NT_ * 32];

    int tid = threadIdx.x;
    int m0 = blockIdx.y * 128;
    int n0 = blockIdx.x * NT_;
    int wid  = tid >> 6, lane = tid & 63;
    int wm   = wid >> 1, wn   = wid & 1;
    int quad = lane >> 4, l15 = lane & 15;

    int h = (blockIdx.x * 2 + wn) * 16 + l15;   // this lane's h column
    float Bi = bi[h], Bfs = bfs[h], Bft = bft[h], Bo = bo[h], Bc = bc[h];

    f32x4 acc[4][5];
    for (int i = 0; i < 4; ++i)
        for (int j = 0; j < 5; ++j)
            acc[i][j] = (f32x4){0.f, 0.f, 0.f, 0.f};

    int srow = tid >> 2;
    int scol = (tid & 3) * 8;
    const __hip_bfloat16* Abase = A  + (size_t)(m0 + srow) * K_ + scol;
    const __hip_bfloat16* Bbase = WT + (size_t)(n0 + srow) * K_ + scol;
    unsigned short* AsDst = sA + tid * 8;
    unsigned short* BsDst = sB + tid * 8;

    for (int k0 = 0; k0 < K_; k0 += 32) {
        GLD16(Abase + k0,                    AsDst);
        GLD16(Abase + k0 + (size_t)64 * K_,  AsDst + 2048);
        GLD16(Bbase + k0,                    BsDst);
        GLD16(Bbase + k0 + (size_t)64 * K_,  BsDst + 2048);
        if (tid < 128)  // rows 128..159 of the B tile
            GLD16(Bbase + k0 + (size_t)128 * K_, BsDst + 4096);
        __syncthreads();

        short8 a[4], b[5];
        for (int f = 0; f < 4; ++f)
            a[f] = *(const short8*)(sA + (wm * 64 + f * 16 + l15) * 32 + quad * 8);
        for (int j = 0; j < 5; ++j)
            b[j] = *(const short8*)(sB + (wn * 80 + j * 16 + l15) * 32 + quad * 8);
        for (int i = 0; i < 4; ++i)
            for (int j = 0; j < 5; ++j)
                acc[i][j] = __builtin_amdgcn_mfma_f32_16x16x32_bf16(a[i], b[j], acc[i][j], 0, 0, 0);
        __syncthreads();
    }

    // Lane-local LSTM epilogue. C/D layout: col = l15 (h), row = quad*4 + r.
    for (int i = 0; i < 4; ++i) {
        int row0 = m0 + wm * 64 + i * 16 + quad * 4;
        for (int r = 0; r < 4; ++r) {
            size_t idx = (size_t)(row0 + r) * H_ + h;
            float i_n  = sigf(acc[i][0][r] + Bi);
            float fs_n = sigf(acc[i][1][r] + Bfs);
            float ft_n = sigf(acc[i][2][r] + Bft);
            float o_n  = sigf(acc[i][3][r] + Bo);
            float c_n  = tanhfast(acc[i][4][r] + Bc);
            float ch   = i_n * c_n + ft_n * ct[idx] + fs_n * cs[idx];
            out[idx] = o_n * tanhfast(ch);
            out[(size_t)B_ * H_ + idx] = ch;
        }
    }
}

// ---------------------------------------------------------------------------
// Fallback (ws too small): one block per row, fp32 direct. Slow but correct.
// ---------------------------------------------------------------------------
struct AllW {
    const float* U[5];
    const float* Wt[5];
    const float* Ws[5];
    const float* bias[5];
};

__global__ __launch_bounds__(512) void fallback_kernel(const float* __restrict__ x,
                                                       const float* __restrict__ ht,
                                                       const float* __restrict__ hs,
                                                       const float* __restrict__ ct,
                                                       const float* __restrict__ cs,
                                                       AllW w, float* __restrict__ out) {
    __shared__ float arow[K_];
    int b = blockIdx.x;
    int h = threadIdx.x;
    for (int k = h; k < K_; k += 512) {
        float v;
        if (k < D_)           v = x[b * D_ + k];
        else if (k < D_ + H_) v = ht[b * H_ + k - D_];
        else                  v = hs[b * H_ + k - D_ - H_];
        arow[k] = v;
    }
    __syncthreads();
    float g[5];
    for (int gi = 0; gi < 5; ++gi) {
        float s = w.bias[gi][h];
        const float* U = w.U[gi];
        for (int k = 0; k < D_; ++k) s += arow[k] * U[(size_t)k * H_ + h];
        const float* Wt = w.Wt[gi];
        for (int k = 0; k < H_; ++k) s += arow[D_ + k] * Wt[(size_t)k * H_ + h];
        const float* Ws = w.Ws[gi];
        for (int k = 0; k < H_; ++k) s += arow[D_ + H_ + k] * Ws[(size_t)k * H_ + h];
        g[gi] = s;
    }
    int idx = b * H_ + h;
    float i_n = sigf(g[0]), fs_n = sigf(g[1]), ft_n = sigf(g[2]), o_n = sigf(g[3]);
    float c_n = tanhfast(g[4]);
    float ch  = i_n * c_n + ft_n * ct[idx] + fs_n * cs[idx];
    out[idx] = o_n * tanhfast(ch);
    out[(size_t)B_ * H_ + idx] = ch;
}

// ---------------------------------------------------------------------------
extern "C" void kernel_launch(void* const* d_in, const int* in_sizes, int n_in,
                              void* d_out, int out_size, void* d_ws, size_t ws_size,
                              hipStream_t stream) {
    const float* x  = (const float*)d_in[0];
    const float* ht = (const float*)d_in[1];
    const float* hs = (const float*)d_in[2];
    const float* ct = (const float*)d_in[3];
    const float* cs = (const float*)d_in[4];

    // weights: d_in[5 + g*4 + {0:U, 1:Wt, 2:Ws, 3:b}], gates g = i, f_s, f_t, o, c
    WPtrs wp;
    AllW  aw;
    const float* bias[5];
    for (int g = 0; g < 5; ++g) {
        wp.U[g]  = (const float*)d_in[5 + g * 4 + 0];
        wp.Wt[g] = (const float*)d_in[5 + g * 4 + 1];
        wp.Ws[g] = (const float*)d_in[5 + g * 4 + 2];
        bias[g]  = (const float*)d_in[5 + g * 4 + 3];
        aw.U[g] = wp.U[g]; aw.Wt[g] = wp.Wt[g]; aw.Ws[g] = wp.Ws[g]; aw.bias[g] = bias[g];
    }
    float* out = (float*)d_out;

    size_t szA = (size_t)B_ * K_ * 2;  // 20 MB
    size_t szW = (size_t)N_ * K_ * 2;  // 6.25 MB

    if (ws_size >= szA + szW) {
        __hip_bfloat16* Abf = (__hip_bfloat16*)d_ws;
        __hip_bfloat16* WT  = (__hip_bfloat16*)((char*)d_ws + szA);

        convA_kernel<<<(B_ * K_ / 8) / 256, 256, 0, stream>>>(x, ht, hs, Abf);
        convW_kernel<<<dim3(8, 20, 5), 256, 0, stream>>>(wp, WT);
        gemm_fused_kernel<<<dim3(N_ / NT_, B_ / 128), 256, 0, stream>>>(
            Abf, WT, ct, cs, bias[0], bias[1], bias[2], bias[3], bias[4], out);
    } else {
        fallback_kernel<<<B_, 512, 0, stream>>>(x, ht, hs, ct, cs, aw, out);
    }
}

// Round 4
// 244.985 us; speedup vs baseline: 1.1909x; 1.0129x over previous
//
#include <hip/hip_runtime.h>
#include <hip/hip_bf16.h>
#include <cstdint>
#include <cstddef>

// Problem constants
#define B_  8192
#define D_  256
#define H_  512
#define K_  1280   // D + 2H
#define N_  2560   // 5H
#define NT_ 160    // N-tile: 2 h-groups of (16 h x 5 gates)

typedef short short8 __attribute__((ext_vector_type(8)));
typedef float f32x4  __attribute__((ext_vector_type(4)));

__device__ __forceinline__ float sigf(float x)     { return 1.f / (1.f + __expf(-x)); }
__device__ __forceinline__ float tanhfast(float x) { return 1.f - 2.f / (__expf(2.f * x) + 1.f); }

// ---------------------------------------------------------------------------
// convA: pack [x | h_t | h_s] -> bf16 A[B_, K_], 8 elems/thread.
// ---------------------------------------------------------------------------
__global__ void convA_kernel(const float* __restrict__ x, const float* __restrict__ ht,
                             const float* __restrict__ hs, __hip_bfloat16* __restrict__ A) {
    int t = blockIdx.x * 256 + threadIdx.x;   // over B_*K_/8 (exact multiple)
    int idx8 = t * 8;
    int b = idx8 / K_;
    int k = idx8 - b * K_;
    const float* src;
    if (k < D_)            src = x  + (size_t)b * D_ + k;
    else if (k < D_ + H_)  src = ht + (size_t)b * H_ + (k - D_);
    else                   src = hs + (size_t)b * H_ + (k - D_ - H_);
    f32x4 v0 = *(const f32x4*)(src);
    f32x4 v1 = *(const f32x4*)(src + 4);
    union { short8 s; __hip_bfloat16 h[8]; } o;
    o.h[0] = __float2bfloat16(v0[0]); o.h[1] = __float2bfloat16(v0[1]);
    o.h[2] = __float2bfloat16(v0[2]); o.h[3] = __float2bfloat16(v0[3]);
    o.h[4] = __float2bfloat16(v1[0]); o.h[5] = __float2bfloat16(v1[1]);
    o.h[6] = __float2bfloat16(v1[2]); o.h[7] = __float2bfloat16(v1[3]);
    *(short8*)(A + idx8) = o.s;
}

// ---------------------------------------------------------------------------
// convW: build bf16 WT[n', k], n' = (h/16)*80 + g*16 + (h%16)  (gate-interleaved)
// ---------------------------------------------------------------------------
struct WPtrs {
    const float* U[5];
    const float* Wt[5];
    const float* Ws[5];
};

__global__ void convW_kernel(WPtrs p, __hip_bfloat16* __restrict__ WT) {
    __shared__ __hip_bfloat16 tile[64][72];  // padded
    int g  = blockIdx.z;
    int k0 = blockIdx.y * 64;
    int h0 = blockIdx.x * 64;
    const float* src; int kl0;
    if (k0 < 256)      { src = p.U[g];  kl0 = k0; }
    else if (k0 < 768) { src = p.Wt[g]; kl0 = k0 - 256; }
    else               { src = p.Ws[g]; kl0 = k0 - 768; }
    int tid = threadIdx.x;
    int tk = tid >> 6;    // 0..3
    int th = tid & 63;
    for (int r = 0; r < 16; ++r) {
        int kl = r * 4 + tk;
        tile[kl][th] = __float2bfloat16(src[(size_t)(kl0 + kl) * H_ + h0 + th]);
    }
    __syncthreads();
    for (int r = 0; r < 16; ++r) {
        int hl = r * 4 + tk;           // h within tile
        int h  = h0 + hl;
        int np = (h >> 4) * 80 + g * 16 + (h & 15);
        WT[(size_t)np * K_ + k0 + th] = tile[th][hl];
    }
}

// ---------------------------------------------------------------------------
// Fused GEMM + LSTM epilogue.
// grid = (B_/128, N_/NT_): blockIdx.x = ROW tile (fastest) so consecutive
// blocks share one W column-tile (400 KB) -> per-XCD L2 working set ~3.4 MB.
// ---------------------------------------------------------------------------
#define GLD16(gp, lp)                                                              \
    __builtin_amdgcn_global_load_lds(                                              \
        (const __attribute__((address_space(1))) unsigned int*)(gp),               \
        (__attribute__((address_space(3))) unsigned int*)(lp), 16, 0, 0)

__global__ __launch_bounds__(256) void gemm_fused_kernel(
    const __hip_bfloat16* __restrict__ A, const __hip_bfloat16* __restrict__ WT,
    const float* __restrict__ ct, const float* __restrict__ cs,
    const float* __restrict__ bi, const float* __restrict__ bfs,
    const float* __restrict__ bft, const float* __restrict__ bo,
    const float* __restrict__ bc, float* __restrict__ out) {
    __shared__ alignas(16) unsigned short sA[128 * 32];
    __shared__ alignas(16) unsigned short sB[NT_ * 32];

    int tid = threadIdx.x;
    int m0 = blockIdx.x * 128;   // row tile (fast axis)
    int n0 = blockIdx.y * NT_;   // W column tile (slow axis)
    int wid  = tid >> 6, lane = tid & 63;
    int wm   = wid >> 1, wn   = wid & 1;
    int quad = lane >> 4, l15 = lane & 15;

    int h = (blockIdx.y * 2 + wn) * 16 + l15;   // this lane's h column
    float Bi = bi[h], Bfs = bfs[h], Bft = bft[h], Bo = bo[h], Bc = bc[h];

    f32x4 acc[4][5];
    for (int i = 0; i < 4; ++i)
        for (int j = 0; j < 5; ++j)
            acc[i][j] = (f32x4){0.f, 0.f, 0.f, 0.f};

    int srow = tid >> 2;
    int scol = (tid & 3) * 8;
    const __hip_bfloat16* Abase = A  + (size_t)(m0 + srow) * K_ + scol;
    const __hip_bfloat16* Bbase = WT + (size_t)(n0 + srow) * K_ + scol;
    unsigned short* AsDst = sA + tid * 8;
    unsigned short* BsDst = sB + tid * 8;

    for (int k0 = 0; k0 < K_; k0 += 32) {
        GLD16(Abase + k0,                    AsDst);
        GLD16(Abase + k0 + (size_t)64 * K_,  AsDst + 2048);
        GLD16(Bbase + k0,                    BsDst);
        GLD16(Bbase + k0 + (size_t)64 * K_,  BsDst + 2048);
        if (tid < 128)  // rows 128..159 of the B tile
            GLD16(Bbase + k0 + (size_t)128 * K_, BsDst + 4096);
        __syncthreads();

        // a-frags stay live (16 VGPR); b-frag loaded one at a time (4 VGPR).
        short8 a[4];
        for (int f = 0; f < 4; ++f)
            a[f] = *(const short8*)(sA + (wm * 64 + f * 16 + l15) * 32 + quad * 8);
        for (int j = 0; j < 5; ++j) {
            short8 b = *(const short8*)(sB + (wn * 80 + j * 16 + l15) * 32 + quad * 8);
            for (int i = 0; i < 4; ++i)
                acc[i][j] = __builtin_amdgcn_mfma_f32_16x16x32_bf16(a[i], b, acc[i][j], 0, 0, 0);
        }
        __syncthreads();
    }

    // Lane-local LSTM epilogue. C/D layout: col = l15 (h), row = quad*4 + r.
    for (int i = 0; i < 4; ++i) {
        int row0 = m0 + wm * 64 + i * 16 + quad * 4;
        for (int r = 0; r < 4; ++r) {
            size_t idx = (size_t)(row0 + r) * H_ + h;
            float i_n  = sigf(acc[i][0][r] + Bi);
            float fs_n = sigf(acc[i][1][r] + Bfs);
            float ft_n = sigf(acc[i][2][r] + Bft);
            float o_n  = sigf(acc[i][3][r] + Bo);
            float c_n  = tanhfast(acc[i][4][r] + Bc);
            float ch   = i_n * c_n + ft_n * ct[idx] + fs_n * cs[idx];
            out[idx] = o_n * tanhfast(ch);
            out[(size_t)B_ * H_ + idx] = ch;
        }
    }
}

// ---------------------------------------------------------------------------
// Fallback (ws too small): one block per row, fp32 direct. Slow but correct.
// ---------------------------------------------------------------------------
struct AllW {
    const float* U[5];
    const float* Wt[5];
    const float* Ws[5];
    const float* bias[5];
};

__global__ __launch_bounds__(512) void fallback_kernel(const float* __restrict__ x,
                                                       const float* __restrict__ ht,
                                                       const float* __restrict__ hs,
                                                       const float* __restrict__ ct,
                                                       const float* __restrict__ cs,
                                                       AllW w, float* __restrict__ out) {
    __shared__ float arow[K_];
    int b = blockIdx.x;
    int h = threadIdx.x;
    for (int k = h; k < K_; k += 512) {
        float v;
        if (k < D_)           v = x[b * D_ + k];
        else if (k < D_ + H_) v = ht[b * H_ + k - D_];
        else                  v = hs[b * H_ + k - D_ - H_];
        arow[k] = v;
    }
    __syncthreads();
    float g[5];
    for (int gi = 0; gi < 5; ++gi) {
        float s = w.bias[gi][h];
        const float* U = w.U[gi];
        for (int k = 0; k < D_; ++k) s += arow[k] * U[(size_t)k * H_ + h];
        const float* Wt = w.Wt[gi];
        for (int k = 0; k < H_; ++k) s += arow[D_ + k] * Wt[(size_t)k * H_ + h];
        const float* Ws = w.Ws[gi];
        for (int k = 0; k < H_; ++k) s += arow[D_ + H_ + k] * Ws[(size_t)k * H_ + h];
        g[gi] = s;
    }
    int idx = b * H_ + h;
    float i_n = sigf(g[0]), fs_n = sigf(g[1]), ft_n = sigf(g[2]), o_n = sigf(g[3]);
    float c_n = tanhfast(g[4]);
    float ch  = i_n * c_n + ft_n * ct[idx] + fs_n * cs[idx];
    out[idx] = o_n * tanhfast(ch);
    out[(size_t)B_ * H_ + idx] = ch;
}

// ---------------------------------------------------------------------------
extern "C" void kernel_launch(void* const* d_in, const int* in_sizes, int n_in,
                              void* d_out, int out_size, void* d_ws, size_t ws_size,
                              hipStream_t stream) {
    const float* x  = (const float*)d_in[0];
    const float* ht = (const float*)d_in[1];
    const float* hs = (const float*)d_in[2];
    const float* ct = (const float*)d_in[3];
    const float* cs = (const float*)d_in[4];

    WPtrs wp;
    AllW  aw;
    const float* bias[5];
    for (int g = 0; g < 5; ++g) {
        wp.U[g]  = (const float*)d_in[5 + g * 4 + 0];
        wp.Wt[g] = (const float*)d_in[5 + g * 4 + 1];
        wp.Ws[g] = (const float*)d_in[5 + g * 4 + 2];
        bias[g]  = (const float*)d_in[5 + g * 4 + 3];
        aw.U[g] = wp.U[g]; aw.Wt[g] = wp.Wt[g]; aw.Ws[g] = wp.Ws[g]; aw.bias[g] = bias[g];
    }
    float* out = (float*)d_out;

    size_t szA = (size_t)B_ * K_ * 2;  // 20 MB
    size_t szW = (size_t)N_ * K_ * 2;  // 6.25 MB

    if (ws_size >= szA + szW) {
        __hip_bfloat16* Abf = (__hip_bfloat16*)d_ws;
        __hip_bfloat16* WT  = (__hip_bfloat16*)((char*)d_ws + szA);

        convA_kernel<<<(B_ * K_ / 8) / 256, 256, 0, stream>>>(x, ht, hs, Abf);
        convW_kernel<<<dim3(8, 20, 5), 256, 0, stream>>>(wp, WT);
        gemm_fused_kernel<<<dim3(B_ / 128, N_ / NT_), 256, 0, stream>>>(
            Abf, WT, ct, cs, bias[0], bias[1], bias[2], bias[3], bias[4], out);
    } else {
        fallback_kernel<<<B_, 512, 0, stream>>>(x, ht, hs, ct, cs, aw, out);
    }
}